// Round 1
// baseline (53.825 us; speedup 1.0000x reference)
//
#include <hip/hip_runtime.h>

// Solve A x = b where A is the 5-point periodic stencil on a 128x64 grid:
//   A[n,n]        = entries_a[n]  (= 4 + |randn|, strictly diagonally dominant)
//   A[n,nbr(n)]   = -1            (4 periodic neighbors; entries_a[N..5N) = -1 by construction)
// A is SPD -> Jacobi-preconditioned CG, entirely inside ONE workgroup (one CU),
// with p staged in LDS for the stencil matvec and block-level reductions.

#define GNX 128
#define GNY 64
#define GN  8192          // GNX * GNY
#define TPB 1024          // 16 waves
#define EPT 8             // elements per thread: TPB * EPT == GN
#define MAXIT 64

__device__ __forceinline__ float block_reduce(float v, float* red, int tid) {
    // wave-level reduce (64 lanes)
    #pragma unroll
    for (int off = 32; off > 0; off >>= 1)
        v += __shfl_down(v, off, 64);
    const int wid  = tid >> 6;   // 0..15
    const int lane = tid & 63;
    __syncthreads();             // protect `red` from previous use
    if (lane == 0) red[wid] = v;
    __syncthreads();
    // every thread sums the 16 wave partials (broadcast LDS reads, no extra sync)
    float s = red[0];
    #pragma unroll
    for (int w = 1; w < 16; ++w) s += red[w];
    return s;
}

__global__ __launch_bounds__(TPB, 1)
void pcg_stencil_kernel(const float* __restrict__ entries,
                        const float* __restrict__ b,
                        float* __restrict__ xout) {
    __shared__ float p_lds[GN];   // 32 KB: search direction, for neighbor gather
    __shared__ float red[16];

    const int tid = threadIdx.x;

    float dg[EPT], id[EPT], xv[EPT], rv[EPT], pv[EPT];
    int njm[EPT], njp[EPT];       // j-wrap neighbor indices (precomputed)

    float rz = 0.f;
    #pragma unroll
    for (int k = 0; k < EPT; ++k) {
        const int e = tid + k * TPB;            // coalesced, j = e & 63 == lane id
        dg[k] = entries[e];                     // diagonal
        id[k] = 1.0f / dg[k];                   // Jacobi preconditioner
        const float bb = b[e];
        xv[k] = 0.f;
        rv[k] = bb;                             // r0 = b (x0 = 0)
        pv[k] = bb * id[k];                     // p0 = z0 = D^-1 r0
        rz   += bb * bb * id[k];                // r0 . z0
        njm[k] = (e & ~(GNY - 1)) | ((e + GNY - 1) & (GNY - 1));  // j-1 mod 64
        njp[k] = (e & ~(GNY - 1)) | ((e + 1)       & (GNY - 1));  // j+1 mod 64
    }
    rz = block_reduce(rz, red, tid);
    const float stop = rz * 1e-12f;

    for (int it = 0; it < MAXIT; ++it) {
        // stage p in LDS (prev-iter reads of p_lds were fenced by the two
        // block_reduce syncs, so this write does not race)
        #pragma unroll
        for (int k = 0; k < EPT; ++k) p_lds[tid + k * TPB] = pv[k];
        __syncthreads();

        // Ap = D.p - (p_left + p_right + p_up + p_down); pAp partial
        float pap = 0.f;
        float Ap[EPT];
        #pragma unroll
        for (int k = 0; k < EPT; ++k) {
            const int e = tid + k * TPB;
            const int nim = (e + GN - GNY) & (GN - 1);   // i-1 mod 128
            const int nip = (e + GNY)      & (GN - 1);   // i+1 mod 128
            const float ap = dg[k] * pv[k]
                           - p_lds[nim]    - p_lds[nip]
                           - p_lds[njm[k]] - p_lds[njp[k]];
            Ap[k] = ap;
            pap  += pv[k] * ap;
        }
        pap = block_reduce(pap, red, tid);

        const float alpha = rz / pap;
        float rznew = 0.f;
        #pragma unroll
        for (int k = 0; k < EPT; ++k) {
            xv[k] += alpha * pv[k];
            rv[k] -= alpha * Ap[k];
            rznew += rv[k] * rv[k] * id[k];      // r . z  with z = D^-1 r
        }
        rznew = block_reduce(rznew, red, tid);

        if (rznew <= stop) break;                // block-uniform -> deterministic

        const float beta = rznew / rz;
        rz = rznew;
        #pragma unroll
        for (int k = 0; k < EPT; ++k)
            pv[k] = rv[k] * id[k] + beta * pv[k];
    }

    #pragma unroll
    for (int k = 0; k < EPT; ++k)
        xout[tid + k * TPB] = xv[k];
}

extern "C" void kernel_launch(void* const* d_in, const int* in_sizes, int n_in,
                              void* d_out, int out_size, void* d_ws, size_t ws_size,
                              hipStream_t stream) {
    const float* entries = (const float*)d_in[0];   // entries_a [5N] f32
    // d_in[1] = indices_a (static stencil, unused), d_in[2] = eps_diag (unused by reference)
    const float* b = (const float*)d_in[3];         // b [N] f32
    float* xout = (float*)d_out;                    // x [N] f32

    pcg_stencil_kernel<<<1, TPB, 0, stream>>>(entries, b, xout);
}

// Round 2
// 30.008 us; speedup vs baseline: 1.7937x; 1.7937x over previous
//
#include <hip/hip_runtime.h>

// Solve A x = b, A = 5-point periodic stencil on 128x64 grid:
//   diag = entries_a[0..N) (= 4+|randn|, SPD, diagonally dominant), offdiag = -1.
// Jacobi-preconditioned CG in ONE workgroup (one CU).
// Layout: j (period 64) = lane -> j-neighbors via DPP wave rotate (VALU, no LDS).
//         i = 16*wave + k (k = register index) -> i-neighbors in-register except
//         2 halo rows per wave exchanged through LDS.
// Reductions: DPP tree per wave (row_shr + row_bcast), 8 partials via LDS.

#define GNX 128
#define GNY 64
#define GN  8192
#define TPB 512
#define NW  8            // waves
#define EPT 16           // i-rows per thread
#define MAXIT 48

// gfx9 DPP ctrl encodings
#define DPP_ROW_SHR1  0x111
#define DPP_ROW_SHR2  0x112
#define DPP_ROW_SHR4  0x114
#define DPP_ROW_SHR8  0x118
#define DPP_BCAST15   0x142
#define DPP_BCAST31   0x143
#define DPP_WAVE_ROL1 0x134
#define DPP_WAVE_ROR1 0x13C

template <int CTRL>
__device__ __forceinline__ float dpp0(float x) {
    // invalid source lanes produce 0 (bound_ctrl=true) -> identity under add
    return __int_as_float(__builtin_amdgcn_update_dpp(
        0, __float_as_int(x), CTRL, 0xF, 0xF, true));
}

// full-wave (64-lane) sum, result uniform via readlane; pure VALU
__device__ __forceinline__ float wave_sum(float v) {
    v += dpp0<DPP_ROW_SHR1>(v);
    v += dpp0<DPP_ROW_SHR2>(v);
    v += dpp0<DPP_ROW_SHR4>(v);
    v += dpp0<DPP_ROW_SHR8>(v);   // lane15 of each 16-row = row sum
    v += dpp0<DPP_BCAST15>(v);    // fold rows 0->1, 2->3
    v += dpp0<DPP_BCAST31>(v);    // fold halves: lane 63 = total
    return __int_as_float(__builtin_amdgcn_readlane(__float_as_int(v), 63));
}

__global__ __launch_bounds__(TPB, 2)
void pcg_stencil_kernel(const float* __restrict__ entries,
                        const float* __restrict__ b,
                        float* __restrict__ xout) {
    __shared__ float halo[NW][2][64];  // [wave][top/bottom row][j]
    __shared__ float redA[NW];         // pap partials
    __shared__ float redB[NW];         // rz partials

    const int tid  = threadIdx.x;
    const int lane = tid & 63;         // = j
    const int w    = tid >> 6;         // wave id; rows i = 16w .. 16w+15

    float dg[EPT], id[EPT], xv[EPT], rv[EPT], pv[EPT], Ap[EPT];

    float rz = 0.f;
    #pragma unroll
    for (int k = 0; k < EPT; ++k) {
        const int e = (w * EPT + k) * GNY + lane;   // coalesced
        dg[k] = entries[e];
        id[k] = 1.0f / dg[k];
        const float bb = b[e];
        xv[k] = 0.f;
        rv[k] = bb;                 // r0 = b (x0 = 0)
        pv[k] = bb * id[k];         // p0 = z0 = D^-1 r0
        rz   += bb * bb * id[k];
    }
    rz = wave_sum(rz);
    if (lane == 0) redB[w] = rz;
    __syncthreads();                                 // BAR0
    {
        const float4* rq = (const float4*)redB;
        const float4 a = rq[0], c = rq[1];
        rz = a.x + a.y + a.z + a.w + c.x + c.y + c.z + c.w;
    }
    const float stop = rz * 1e-10f;

    for (int it = 0; it < MAXIT; ++it) {
        // publish halo rows (prev-iter halo reads fenced by BAR2+BAR3)
        halo[w][0][lane] = pv[0];
        halo[w][1][lane] = pv[EPT - 1];
        __syncthreads();                             // BAR1
        const float up   = halo[(w + NW - 1) & (NW - 1)][1][lane]; // row 16w-1
        const float down = halo[(w + 1) & (NW - 1)][0][lane];      // row 16w+16

        // Ap = D.p - (p_jm + p_jp + p_im + p_ip); j via DPP rotate, i via regs
        float pap = 0.f;
        #pragma unroll
        for (int k = 0; k < EPT; ++k) {
            const float jl  = dpp0<DPP_WAVE_ROR1>(pv[k]);
            const float jr  = dpp0<DPP_WAVE_ROL1>(pv[k]);
            const float iu  = (k == 0)       ? up   : pv[k - 1];
            const float idn = (k == EPT - 1) ? down : pv[k + 1];
            const float ap  = dg[k] * pv[k] - (jl + jr + iu + idn);
            Ap[k] = ap;
            pap  += pv[k] * ap;
        }
        pap = wave_sum(pap);
        if (lane == 0) redA[w] = pap;
        __syncthreads();                             // BAR2
        {
            const float4* rq = (const float4*)redA;
            const float4 a = rq[0], c = rq[1];
            pap = a.x + a.y + a.z + a.w + c.x + c.y + c.z + c.w;
        }

        const float alpha = rz / pap;
        float rznew = 0.f;
        #pragma unroll
        for (int k = 0; k < EPT; ++k) {
            xv[k] += alpha * pv[k];
            rv[k] -= alpha * Ap[k];
            rznew += rv[k] * rv[k] * id[k];          // r.z, z = D^-1 r
        }
        rznew = wave_sum(rznew);
        if (lane == 0) redB[w] = rznew;
        __syncthreads();                             // BAR3
        {
            const float4* rq = (const float4*)redB;
            const float4 a = rq[0], c = rq[1];
            rznew = a.x + a.y + a.z + a.w + c.x + c.y + c.z + c.w;
        }

        if (rznew <= stop) break;                    // block-uniform

        const float beta = rznew / rz;
        rz = rznew;
        #pragma unroll
        for (int k = 0; k < EPT; ++k)
            pv[k] = rv[k] * id[k] + beta * pv[k];
    }

    #pragma unroll
    for (int k = 0; k < EPT; ++k)
        xout[(w * EPT + k) * GNY + lane] = xv[k];
}

extern "C" void kernel_launch(void* const* d_in, const int* in_sizes, int n_in,
                              void* d_out, int out_size, void* d_ws, size_t ws_size,
                              hipStream_t stream) {
    const float* entries = (const float*)d_in[0];   // entries_a [5N] f32
    // d_in[1] = indices_a (static stencil), d_in[2] = eps_diag (unused by reference)
    const float* b = (const float*)d_in[3];         // b [N] f32
    float* xout = (float*)d_out;                    // x [N] f32

    pcg_stencil_kernel<<<1, TPB, 0, stream>>>(entries, b, xout);
}

// Round 3
// 27.804 us; speedup vs baseline: 1.9358x; 1.0792x over previous
//
#include <hip/hip_runtime.h>

// Solve A x = b, A = 5-point periodic stencil on 128x64 grid (SPD, diag-dominant).
// Symmetrically scaled CG (S = D^-1/2 A D^-1/2, identity preconditioner) in the
// Chronopoulos-Gear single-reduction form: ONE reduction + TWO barriers per iter.
// One workgroup (one CU). j (period 64) = lane -> j-neighbors via DPP wave
// rotate; i = 16*wave + k in registers, 2 halo rows per wave through LDS.

#define GNY 64
#define GN  8192
#define TPB 512
#define NW  8            // waves
#define EPT 16           // i-rows per thread
#define MAXIT 48

// gfx9 DPP ctrl encodings
#define DPP_ROW_SHR1  0x111
#define DPP_ROW_SHR2  0x112
#define DPP_ROW_SHR4  0x114
#define DPP_ROW_SHR8  0x118
#define DPP_BCAST15   0x142
#define DPP_BCAST31   0x143
#define DPP_WAVE_ROL1 0x134
#define DPP_WAVE_ROR1 0x13C

template <int CTRL>
__device__ __forceinline__ float dpp0(float x) {
    // bound_ctrl=true: invalid source lanes read 0 -> identity under add
    return __int_as_float(__builtin_amdgcn_update_dpp(
        0, __float_as_int(x), CTRL, 0xF, 0xF, true));
}

// two independent 64-lane sums, DPP chains interleave; totals land in lane 63
__device__ __forceinline__ void wave_sum2(float& a, float& b) {
    a += dpp0<DPP_ROW_SHR1>(a); b += dpp0<DPP_ROW_SHR1>(b);
    a += dpp0<DPP_ROW_SHR2>(a); b += dpp0<DPP_ROW_SHR2>(b);
    a += dpp0<DPP_ROW_SHR4>(a); b += dpp0<DPP_ROW_SHR4>(b);
    a += dpp0<DPP_ROW_SHR8>(a); b += dpp0<DPP_ROW_SHR8>(b);
    a += dpp0<DPP_BCAST15>(a);  b += dpp0<DPP_BCAST15>(b);
    a += dpp0<DPP_BCAST31>(a);  b += dpp0<DPP_BCAST31>(b);
}

__global__ __launch_bounds__(TPB, 2)
void pcg_stencil_kernel(const float* __restrict__ entries,
                        const float* __restrict__ bvec,
                        float* __restrict__ xout) {
    __shared__ float halo[NW][2][64];          // [wave][top/bottom row][j]
    __shared__ __align__(16) float2 red[NW];   // {gamma, delta} partials

    const int tid  = threadIdx.x;
    const int lane = tid & 63;     // = j
    const int w    = tid >> 6;     // wave id; rows i = 16w .. 16w+15

    float isd[EPT], xv[EPT], rv[EPT], wv[EPT], pv[EPT], sv[EPT];

    float gp = 0.f;                // gamma partial = r.r (scaled space)
    #pragma unroll
    for (int k = 0; k < EPT; ++k) {
        const int e = (w * EPT + k) * GNY + lane;   // coalesced
        isd[k] = rsqrtf(entries[e]);                // D^-1/2 (any pos diag is exact)
        rv[k]  = bvec[e] * isd[k];                  // r0 = b' (x0 = 0)
        xv[k] = 0.f; pv[k] = 0.f; sv[k] = 0.f;
        gp += rv[k] * rv[k];
    }

    float alpha = 0.f, beta = 0.f, gam = 0.f, stop = 0.f;

    for (int it = 0; it <= MAXIT; ++it) {
        // t = isd .* r ; publish halo rows (prev-iter reads fenced by BAR-R)
        float tv[EPT];
        #pragma unroll
        for (int k = 0; k < EPT; ++k) tv[k] = isd[k] * rv[k];
        halo[w][0][lane] = tv[0];
        halo[w][1][lane] = tv[EPT - 1];

        // w = S r = r - isd .* (sum of 4 neighbors of t); delta = r.w
        // interior rows + boundary-row partials BEFORE the barrier
        float dp = 0.f;
        #pragma unroll
        for (int k = 1; k < EPT - 1; ++k) {
            const float sum4 = dpp0<DPP_WAVE_ROR1>(tv[k]) + dpp0<DPP_WAVE_ROL1>(tv[k])
                             + tv[k - 1] + tv[k + 1];
            wv[k] = rv[k] - isd[k] * sum4;
            dp   += rv[k] * wv[k];
        }
        const float sum30 = dpp0<DPP_WAVE_ROR1>(tv[0]) + dpp0<DPP_WAVE_ROL1>(tv[0])
                          + tv[1];
        const float sum3f = dpp0<DPP_WAVE_ROR1>(tv[EPT-1]) + dpp0<DPP_WAVE_ROL1>(tv[EPT-1])
                          + tv[EPT - 2];
        __syncthreads();                                        // BAR-H
        const float up   = halo[(w + NW - 1) & (NW - 1)][1][lane]; // row 16w-1
        const float down = halo[(w + 1) & (NW - 1)][0][lane];      // row 16w+16
        wv[0]       = rv[0]       - isd[0]       * (sum30 + up);
        wv[EPT - 1] = rv[EPT - 1] - isd[EPT - 1] * (sum3f + down);
        dp += rv[0] * wv[0] + rv[EPT - 1] * wv[EPT - 1];

        // ONE fused reduction for {gamma, delta}
        wave_sum2(gp, dp);
        if (lane == 63) red[w] = make_float2(gp, dp);
        __syncthreads();                                        // BAR-R
        float gnew, dnew;
        {
            const float4* rq = (const float4*)red;
            const float4 q0 = rq[0], q1 = rq[1], q2 = rq[2], q3 = rq[3];
            const float4 q  = make_float4(q0.x + q1.x + q2.x + q3.x,
                                          q0.y + q1.y + q2.y + q3.y,
                                          q0.z + q1.z + q2.z + q3.z,
                                          q0.w + q1.w + q2.w + q3.w);
            gnew = q.x + q.z;
            dnew = q.y + q.w;
        }

        if (it == 0) {
            beta = 0.f; alpha = gnew / dnew; stop = gnew * 1e-9f;
        } else {
            if (gnew <= stop) break;          // block-uniform -> deterministic
            beta  = gnew / gam;
            alpha = gnew / (dnew - beta * gnew / alpha);  // CG-CG recurrence
        }
        gam = gnew;

        // vector updates; gamma for NEXT iteration fused into the r update
        float gpn = 0.f;
        #pragma unroll
        for (int k = 0; k < EPT; ++k) {
            pv[k] = rv[k] + beta * pv[k];
            sv[k] = wv[k] + beta * sv[k];     // s = S p by recurrence
            xv[k] += alpha * pv[k];
            rv[k] -= alpha * sv[k];
            gpn   += rv[k] * rv[k];
        }
        gp = gpn;
    }

    // unscale: x = isd .* x'
    #pragma unroll
    for (int k = 0; k < EPT; ++k)
        xout[(w * EPT + k) * GNY + lane] = isd[k] * xv[k];
}

extern "C" void kernel_launch(void* const* d_in, const int* in_sizes, int n_in,
                              void* d_out, int out_size, void* d_ws, size_t ws_size,
                              hipStream_t stream) {
    const float* entries = (const float*)d_in[0];   // entries_a [5N] f32 (diag first N)
    // d_in[1] = indices_a (static stencil), d_in[2] = eps_diag (unused by reference)
    const float* b = (const float*)d_in[3];         // b [N] f32
    float* xout = (float*)d_out;                    // x [N] f32

    pcg_stencil_kernel<<<1, TPB, 0, stream>>>(entries, b, xout);
}

// Round 4
// 26.146 us; speedup vs baseline: 2.0586x; 1.0634x over previous
//
#include <hip/hip_runtime.h>

// Solve A x = b, A = 5-point periodic stencil on 128x64 grid (SPD, diag-dominant).
// Symmetrically scaled system S = D^-1/2 A D^-1/2 solved with Ghysels-Vanroose
// PIPELINED CG: ONE reduction + ONE barrier per iteration (reduction result is
// consumed only after the matvec, so its LDS round-trip hides under stencil
// compute). One workgroup (one CU). j (period 64) = lane -> j-neighbors via DPP
// wave rotate; i = 16*wave + k in registers; 2 halo rows/wave via LDS,
// double-buffered by iteration parity so one barrier fences everything.

#define GNY 64
#define GN  8192
#define TPB 512
#define NW  8            // waves
#define EPT 16           // i-rows per thread
#define MAXIT 44

// gfx9 DPP ctrl encodings
#define DPP_ROW_SHR1  0x111
#define DPP_ROW_SHR2  0x112
#define DPP_ROW_SHR4  0x114
#define DPP_ROW_SHR8  0x118
#define DPP_BCAST15   0x142
#define DPP_BCAST31   0x143
#define DPP_WAVE_ROL1 0x134
#define DPP_WAVE_ROR1 0x13C

template <int CTRL>
__device__ __forceinline__ float dpp0(float x) {
    // bound_ctrl=true: invalid source lanes read 0 -> identity under add
    return __int_as_float(__builtin_amdgcn_update_dpp(
        0, __float_as_int(x), CTRL, 0xF, 0xF, true));
}

// two independent 64-lane sums (chains interleave); totals land in lane 63
__device__ __forceinline__ void wave_sum2(float& a, float& b) {
    a += dpp0<DPP_ROW_SHR1>(a); b += dpp0<DPP_ROW_SHR1>(b);
    a += dpp0<DPP_ROW_SHR2>(a); b += dpp0<DPP_ROW_SHR2>(b);
    a += dpp0<DPP_ROW_SHR4>(a); b += dpp0<DPP_ROW_SHR4>(b);
    a += dpp0<DPP_ROW_SHR8>(a); b += dpp0<DPP_ROW_SHR8>(b);
    a += dpp0<DPP_BCAST15>(a);  b += dpp0<DPP_BCAST15>(b);
    a += dpp0<DPP_BCAST31>(a);  b += dpp0<DPP_BCAST31>(b);
}

__device__ __forceinline__ float frcp(float x) { return __builtin_amdgcn_rcpf(x); }

__global__ __launch_bounds__(TPB, 2)
void pcg_pipe_kernel(const float* __restrict__ entries,
                     const float* __restrict__ bvec,
                     float* __restrict__ xout) {
    __shared__ float halo[2][NW][2][64];        // [parity][wave][top/bot][j]
    __shared__ __align__(16) float2 red[2][NW]; // [parity][wave] {gamma,delta}

    const int tid  = threadIdx.x;
    const int lane = tid & 63;     // = j
    const int w    = tid >> 6;     // wave id; rows i = 16w .. 16w+15

    float isd[EPT], xv[EPT], rv[EPT], wv[EPT], zv[EPT], sv[EPT], pv[EPT];
    float tv[EPT], nv[EPT];

    // ---- init: r0 = isd.*b ; w0 = S r0 ; z=s=p=0 ; gamma/delta partials ----
    float gp = 0.f;
    #pragma unroll
    for (int k = 0; k < EPT; ++k) {
        const int e = (w * EPT + k) * GNY + lane;   // coalesced
        isd[k] = rsqrtf(entries[e]);                // D^-1/2 (exact solve for any pos diag)
        rv[k]  = bvec[e] * isd[k];
        xv[k] = 0.f; zv[k] = 0.f; sv[k] = 0.f; pv[k] = 0.f;
        gp   += rv[k] * rv[k];
        tv[k] = isd[k] * rv[k];
    }
    halo[1][w][0][lane] = tv[0];                    // init uses parity-1 buffer
    halo[1][w][1][lane] = tv[EPT - 1];
    float dp = 0.f;
    #pragma unroll
    for (int k = 1; k < EPT - 1; ++k) {
        const float sum4 = dpp0<DPP_WAVE_ROR1>(tv[k]) + dpp0<DPP_WAVE_ROL1>(tv[k])
                         + tv[k - 1] + tv[k + 1];
        wv[k] = rv[k] - isd[k] * sum4;
        dp   += rv[k] * wv[k];
    }
    {
        const float s30 = dpp0<DPP_WAVE_ROR1>(tv[0]) + dpp0<DPP_WAVE_ROL1>(tv[0]) + tv[1];
        const float s3f = dpp0<DPP_WAVE_ROR1>(tv[EPT-1]) + dpp0<DPP_WAVE_ROL1>(tv[EPT-1]) + tv[EPT-2];
        __syncthreads();
        const float up = halo[1][(w + NW - 1) & (NW - 1)][1][lane];
        const float dn = halo[1][(w + 1) & (NW - 1)][0][lane];
        wv[0]       = rv[0]       - isd[0]       * (s30 + up);
        wv[EPT - 1] = rv[EPT - 1] - isd[EPT - 1] * (s3f + dn);
        dp += rv[0] * wv[0] + rv[EPT - 1] * wv[EPT - 1];
    }

    float alpha = 0.f, beta = 0.f, ialpha = 0.f, rgam = 0.f, stop = 0.f;

    for (int it = 0; it < MAXIT; ++it) {
        const int par = it & 1;

        // 1) reduce {gamma, delta} partials (from prev update / init)
        wave_sum2(gp, dp);
        if (lane == 63) red[par][w] = make_float2(gp, dp);

        // 2) t = isd.*w ; publish halo (parity buffer)
        #pragma unroll
        for (int k = 0; k < EPT; ++k) tv[k] = isd[k] * wv[k];
        halo[par][w][0][lane] = tv[0];
        halo[par][w][1][lane] = tv[EPT - 1];

        // 3) interior rows of n = S w  (overlaps the reduction round-trip)
        #pragma unroll
        for (int k = 1; k < EPT - 1; ++k) {
            const float sum4 = dpp0<DPP_WAVE_ROR1>(tv[k]) + dpp0<DPP_WAVE_ROL1>(tv[k])
                             + tv[k - 1] + tv[k + 1];
            nv[k] = wv[k] - isd[k] * sum4;
        }
        const float s30 = dpp0<DPP_WAVE_ROR1>(tv[0]) + dpp0<DPP_WAVE_ROL1>(tv[0]) + tv[1];
        const float s3f = dpp0<DPP_WAVE_ROR1>(tv[EPT-1]) + dpp0<DPP_WAVE_ROL1>(tv[EPT-1]) + tv[EPT-2];

        __syncthreads();                            // THE barrier

        // 4) boundary rows from halo
        const float up = halo[par][(w + NW - 1) & (NW - 1)][1][lane];
        const float dn = halo[par][(w + 1) & (NW - 1)][0][lane];
        nv[0]       = wv[0]       - isd[0]       * (s30 + up);
        nv[EPT - 1] = wv[EPT - 1] - isd[EPT - 1] * (s3f + dn);

        // 5) read reduction; scalars via v_rcp
        float gnew, dnew;
        {
            const float4* rq = (const float4*)red[par];  // {g,d,g,d} x4
            const float4 q0 = rq[0], q1 = rq[1], q2 = rq[2], q3 = rq[3];
            gnew = (q0.x + q0.z) + (q1.x + q1.z) + (q2.x + q2.z) + (q3.x + q3.z);
            dnew = (q0.y + q0.w) + (q1.y + q1.w) + (q2.y + q2.w) + (q3.y + q3.w);
        }
        if (it == 0) {
            beta = 0.f;
            const float rg = frcp(gnew);
            alpha  = gnew * frcp(dnew);
            ialpha = dnew * rg;                     // 1/alpha
            rgam   = rg;                            // 1/gamma
            stop   = gnew * 3e-9f;
        } else {
            if (gnew <= stop) break;                // block-uniform -> deterministic
            const float rg = frcp(gnew);
            beta = gnew * rgam;
            const float denom = dnew - beta * gnew * ialpha;
            alpha  = gnew * frcp(denom);
            ialpha = denom * rg;
            rgam   = rg;
        }

        // 6) recurrences + next iteration's dot partials fused
        float gpn = 0.f, dpn = 0.f;
        #pragma unroll
        for (int k = 0; k < EPT; ++k) {
            zv[k] = nv[k] + beta * zv[k];           // z = S s
            sv[k] = wv[k] + beta * sv[k];           // s = S p
            pv[k] = rv[k] + beta * pv[k];
            xv[k] += alpha * pv[k];
            rv[k] -= alpha * sv[k];
            wv[k] -= alpha * zv[k];                 // w = S r
            gpn += rv[k] * rv[k];
            dpn += wv[k] * rv[k];
        }
        gp = gpn; dp = dpn;
    }

    // unscale: x = isd .* x'
    #pragma unroll
    for (int k = 0; k < EPT; ++k)
        xout[(w * EPT + k) * GNY + lane] = isd[k] * xv[k];
}

extern "C" void kernel_launch(void* const* d_in, const int* in_sizes, int n_in,
                              void* d_out, int out_size, void* d_ws, size_t ws_size,
                              hipStream_t stream) {
    const float* entries = (const float*)d_in[0];   // entries_a [5N] f32 (diag first N)
    // d_in[1] = indices_a (static stencil), d_in[2] = eps_diag (unused by reference)
    const float* b = (const float*)d_in[3];         // b [N] f32
    float* xout = (float*)d_out;                    // x [N] f32

    pcg_pipe_kernel<<<1, TPB, 0, stream>>>(entries, b, xout);
}

// Round 5
// 20.649 us; speedup vs baseline: 2.6067x; 1.2662x over previous
//
#include <hip/hip_runtime.h>

// Solve A x = b, A = 5-point periodic stencil on 128x64 grid (SPD, strictly
// diagonally dominant). Scaled system S = D^-1/2 A D^-1/2 has lambda in (0,2),
// so M^-1 = 2I - S is an SPD Neumann preconditioner: spectrum mu = 1-(1-l)^2
// folds both ends together (kappa ~16 -> ~4.7, ~10 outer iters instead of 20).
// Chronopoulos-Gear single-reduction PCG; 2 stencil applies + 1 reduction +
// 3 barriers per outer. One workgroup, 1024 threads = 16 waves (4/SIMD for
// latency hiding). j (=lane) neighbors via DPP wave rotate; i = 8*wave + k in
// registers; 2 halo rows/wave via LDS (separate buffers per phase, race-free
// under the 3-barrier cycle).

#define GNY 64
#define GN  8192
#define TPB 1024
#define NW  16           // waves
#define EPT 8            // i-rows per thread
#define MAXIT 16

// gfx9 DPP ctrl encodings
#define DPP_ROW_SHR1  0x111
#define DPP_ROW_SHR2  0x112
#define DPP_ROW_SHR4  0x114
#define DPP_ROW_SHR8  0x118
#define DPP_BCAST15   0x142
#define DPP_BCAST31   0x143
#define DPP_WAVE_ROL1 0x134
#define DPP_WAVE_ROR1 0x13C

template <int CTRL>
__device__ __forceinline__ float dpp0(float x) {
    // bound_ctrl=true: invalid source lanes read 0 -> identity under add
    return __int_as_float(__builtin_amdgcn_update_dpp(
        0, __float_as_int(x), CTRL, 0xF, 0xF, true));
}

// two independent 64-lane sums (chains interleave); totals land in lane 63
__device__ __forceinline__ void wave_sum2(float& a, float& b) {
    a += dpp0<DPP_ROW_SHR1>(a); b += dpp0<DPP_ROW_SHR1>(b);
    a += dpp0<DPP_ROW_SHR2>(a); b += dpp0<DPP_ROW_SHR2>(b);
    a += dpp0<DPP_ROW_SHR4>(a); b += dpp0<DPP_ROW_SHR4>(b);
    a += dpp0<DPP_ROW_SHR8>(a); b += dpp0<DPP_ROW_SHR8>(b);
    a += dpp0<DPP_BCAST15>(a);  b += dpp0<DPP_BCAST15>(b);
    a += dpp0<DPP_BCAST31>(a);  b += dpp0<DPP_BCAST31>(b);
}

// sum of 16 values sitting in lanes (lane&15) groups; totals -> lane 15 of row
__device__ __forceinline__ void row_sum16_2(float& a, float& b) {
    a += dpp0<DPP_ROW_SHR1>(a); b += dpp0<DPP_ROW_SHR1>(b);
    a += dpp0<DPP_ROW_SHR2>(a); b += dpp0<DPP_ROW_SHR2>(b);
    a += dpp0<DPP_ROW_SHR4>(a); b += dpp0<DPP_ROW_SHR4>(b);
    a += dpp0<DPP_ROW_SHR8>(a); b += dpp0<DPP_ROW_SHR8>(b);
}

__device__ __forceinline__ float frcp(float x) { return __builtin_amdgcn_rcpf(x); }
__device__ __forceinline__ float rdlane(float x, int l) {
    return __int_as_float(__builtin_amdgcn_readlane(__float_as_int(x), l));
}

__global__ __launch_bounds__(TPB, 4)
void pcg_neumann_kernel(const float* __restrict__ entries,
                        const float* __restrict__ bvec,
                        float* __restrict__ xout) {
    __shared__ float halo1[NW][2][64];          // phase-1 halos
    __shared__ float halo2[NW][2][64];          // phase-2 halos
    __shared__ __align__(8) float2 red[NW];     // {gamma, delta} partials

    const int tid  = threadIdx.x;
    const int lane = tid & 63;     // = j
    const int w    = tid >> 6;     // wave id; rows i = 8w .. 8w+7

    float isd[EPT], xv[EPT], rv[EPT], uv[EPT], wv[EPT], pv[EPT], sv[EPT], tv[EPT];

    #pragma unroll
    for (int k = 0; k < EPT; ++k) {
        const int e = (w * EPT + k) * GNY + lane;   // coalesced
        isd[k] = rsqrtf(entries[e]);                // D^-1/2 (exact for any pos diag)
        rv[k]  = bvec[e] * isd[k];                  // r0 = b' (x0 = 0)
        xv[k] = 0.f; pv[k] = 0.f; sv[k] = 0.f;
    }

    float alpha = 0.f, ialpha = 0.f, rgam = 0.f, stop = 0.f;

    for (int it = 0; it < MAXIT; ++it) {
        // ---- phase 1: u = M^-1 r = r + isd.*Adj(isd.*r) ; gamma = r.u ----
        #pragma unroll
        for (int k = 0; k < EPT; ++k) tv[k] = isd[k] * rv[k];
        halo1[w][0][lane] = tv[0];
        halo1[w][1][lane] = tv[EPT - 1];
        float gp = 0.f;
        #pragma unroll
        for (int k = 1; k < EPT - 1; ++k) {
            const float s4 = dpp0<DPP_WAVE_ROR1>(tv[k]) + dpp0<DPP_WAVE_ROL1>(tv[k])
                           + tv[k - 1] + tv[k + 1];
            uv[k] = fmaf(isd[k], s4, rv[k]);
            gp   += rv[k] * uv[k];
        }
        const float a30 = dpp0<DPP_WAVE_ROR1>(tv[0]) + dpp0<DPP_WAVE_ROL1>(tv[0]) + tv[1];
        const float a3f = dpp0<DPP_WAVE_ROR1>(tv[EPT-1]) + dpp0<DPP_WAVE_ROL1>(tv[EPT-1]) + tv[EPT-2];
        __syncthreads();                                        // BAR1
        {
            const float up = halo1[(w + NW - 1) & (NW - 1)][1][lane];
            const float dn = halo1[(w + 1) & (NW - 1)][0][lane];
            uv[0]       = fmaf(isd[0],       a30 + up, rv[0]);
            uv[EPT - 1] = fmaf(isd[EPT - 1], a3f + dn, rv[EPT - 1]);
            gp += rv[0] * uv[0] + rv[EPT - 1] * uv[EPT - 1];
        }

        // ---- phase 2: w = S u = u - isd.*Adj(isd.*u) ; delta = u.w ----
        #pragma unroll
        for (int k = 0; k < EPT; ++k) tv[k] = isd[k] * uv[k];
        halo2[w][0][lane] = tv[0];
        halo2[w][1][lane] = tv[EPT - 1];
        float dp = 0.f;
        #pragma unroll
        for (int k = 1; k < EPT - 1; ++k) {
            const float s4 = dpp0<DPP_WAVE_ROR1>(tv[k]) + dpp0<DPP_WAVE_ROL1>(tv[k])
                           + tv[k - 1] + tv[k + 1];
            wv[k] = fmaf(-isd[k], s4, uv[k]);
            dp   += uv[k] * wv[k];
        }
        const float b30 = dpp0<DPP_WAVE_ROR1>(tv[0]) + dpp0<DPP_WAVE_ROL1>(tv[0]) + tv[1];
        const float b3f = dpp0<DPP_WAVE_ROR1>(tv[EPT-1]) + dpp0<DPP_WAVE_ROL1>(tv[EPT-1]) + tv[EPT-2];
        __syncthreads();                                        // BAR2
        {
            const float up = halo2[(w + NW - 1) & (NW - 1)][1][lane];
            const float dn = halo2[(w + 1) & (NW - 1)][0][lane];
            wv[0]       = fmaf(-isd[0],       b30 + up, uv[0]);
            wv[EPT - 1] = fmaf(-isd[EPT - 1], b3f + dn, uv[EPT - 1]);
            dp += uv[0] * wv[0] + uv[EPT - 1] * wv[EPT - 1];
        }

        // ---- one fused reduction {gamma, delta} ----
        wave_sum2(gp, dp);                          // totals in lane 63
        if (lane == 63) red[w] = make_float2(gp, dp);
        __syncthreads();                                        // BAR3
        float ga, da;
        {
            const float2 pr = red[lane & (NW - 1)]; // broadcast ds_read_b64
            ga = pr.x; da = pr.y;
            row_sum16_2(ga, da);                    // totals in lane 15 of each row
            ga = rdlane(ga, 15);
            da = rdlane(da, 15);
        }

        float beta;
        if (it == 0) {
            beta = 0.f;
            const float rg = frcp(ga);
            alpha  = ga * frcp(da);
            ialpha = da * rg;                       // 1/alpha
            rgam   = rg;                            // 1/gamma
            stop   = ga * 1e-8f;
        } else {
            if (ga <= stop) break;                  // block-uniform -> deterministic
            const float rg = frcp(ga);
            beta = ga * rgam;
            const float denom = da - beta * ga * ialpha;
            alpha  = ga * frcp(denom);
            ialpha = denom * rg;
            rgam   = rg;
        }

        // ---- recurrences (s = S p maintained exactly: s = w + beta*s) ----
        #pragma unroll
        for (int k = 0; k < EPT; ++k) {
            pv[k] = fmaf(beta,  pv[k], uv[k]);
            sv[k] = fmaf(beta,  sv[k], wv[k]);
            xv[k] = fmaf(alpha, pv[k], xv[k]);
            rv[k] = fmaf(-alpha, sv[k], rv[k]);
        }
    }

    // unscale: x = isd .* x'
    #pragma unroll
    for (int k = 0; k < EPT; ++k)
        xout[(w * EPT + k) * GNY + lane] = isd[k] * xv[k];
}

extern "C" void kernel_launch(void* const* d_in, const int* in_sizes, int n_in,
                              void* d_out, int out_size, void* d_ws, size_t ws_size,
                              hipStream_t stream) {
    const float* entries = (const float*)d_in[0];   // entries_a [5N] f32 (diag first N)
    // d_in[1] = indices_a (static stencil), d_in[2] = eps_diag (unused by reference)
    const float* b = (const float*)d_in[3];         // b [N] f32
    float* xout = (float*)d_out;                    // x [N] f32

    pcg_neumann_kernel<<<1, TPB, 0, stream>>>(entries, b, xout);
}

// Round 6
// 18.587 us; speedup vs baseline: 2.8959x; 1.1110x over previous
//
#include <hip/hip_runtime.h>

// Solve A x = b, A = 5-point periodic stencil on 128x64 grid (SPD, strictly
// diagonally dominant). Scaled system S = D^-1/2 A D^-1/2 has lambda in (0,2);
// M^-1 = 2I - S is an SPD Neumann preconditioner folding the spectrum
// (kappa ~16 -> ~5, ~9-10 outers). Chronopoulos-Gear single-reduction PCG:
// 2 stencil applies + 1 fused reduction + 3 barriers per outer. One workgroup,
// 1024 threads = 16 waves (4/SIMD = hw max for one block). j (=lane) neighbors
// via DPP wave rotate; i = 8*wave + k in registers; 2 halo rows/wave via LDS.
// Elementwise loops (t-scaling, dots, recurrences) packed as f32x2 ->
// v_pk_{mul,fma}_f32; stencil core stays scalar with DPP-fused adds.

#define GNY 64
#define TPB 1024
#define NW  16           // waves
#define EPT 8            // i-rows per thread
#define EPH 4            // f32x2 pairs per thread
#define MAXIT 16

typedef float f32x2 __attribute__((ext_vector_type(2)));

// gfx9 DPP ctrl encodings
#define DPP_ROW_SHR1  0x111
#define DPP_ROW_SHR2  0x112
#define DPP_ROW_SHR4  0x114
#define DPP_ROW_SHR8  0x118
#define DPP_BCAST15   0x142
#define DPP_BCAST31   0x143
#define DPP_WAVE_ROL1 0x134
#define DPP_WAVE_ROR1 0x13C

template <int CTRL>
__device__ __forceinline__ float dpp0(float x) {
    // bound_ctrl=true: invalid source lanes read 0 -> identity under add
    return __int_as_float(__builtin_amdgcn_update_dpp(
        0, __float_as_int(x), CTRL, 0xF, 0xF, true));
}

// two independent 64-lane sums (chains interleave); totals land in lane 63
__device__ __forceinline__ void wave_sum2(float& a, float& b) {
    a += dpp0<DPP_ROW_SHR1>(a); b += dpp0<DPP_ROW_SHR1>(b);
    a += dpp0<DPP_ROW_SHR2>(a); b += dpp0<DPP_ROW_SHR2>(b);
    a += dpp0<DPP_ROW_SHR4>(a); b += dpp0<DPP_ROW_SHR4>(b);
    a += dpp0<DPP_ROW_SHR8>(a); b += dpp0<DPP_ROW_SHR8>(b);
    a += dpp0<DPP_BCAST15>(a);  b += dpp0<DPP_BCAST15>(b);
    a += dpp0<DPP_BCAST31>(a);  b += dpp0<DPP_BCAST31>(b);
}

// fold 16 partials sitting in lane&15 slots; totals -> lane 15 of each row
__device__ __forceinline__ void row_sum16_2(float& a, float& b) {
    a += dpp0<DPP_ROW_SHR1>(a); b += dpp0<DPP_ROW_SHR1>(b);
    a += dpp0<DPP_ROW_SHR2>(a); b += dpp0<DPP_ROW_SHR2>(b);
    a += dpp0<DPP_ROW_SHR4>(a); b += dpp0<DPP_ROW_SHR4>(b);
    a += dpp0<DPP_ROW_SHR8>(a); b += dpp0<DPP_ROW_SHR8>(b);
}

__device__ __forceinline__ float frcp(float x) { return __builtin_amdgcn_rcpf(x); }
__device__ __forceinline__ float rdlane(float x, int l) {
    return __int_as_float(__builtin_amdgcn_readlane(__float_as_int(x), l));
}

// constant-index access into packed pairs (stays in VGPRs after full unroll)
#define AT(a, k) a[(k) >> 1][(k) & 1]

__global__ __launch_bounds__(TPB, 4)
void pcg_neumann_kernel(const float* __restrict__ entries,
                        const float* __restrict__ bvec,
                        float* __restrict__ xout) {
    __shared__ float halo1[NW][2][64];          // phase-1 halos
    __shared__ float halo2[NW][2][64];          // phase-2 halos
    __shared__ __align__(8) float2 red[NW];     // {gamma, delta} partials

    const int tid  = threadIdx.x;
    const int lane = tid & 63;     // = j
    const int w    = tid >> 6;     // wave id; rows i = 8w .. 8w+7

    f32x2 isd2[EPH], xv2[EPH], rv2[EPH], uv2[EPH], wv2[EPH], pv2[EPH], sv2[EPH], tv2[EPH];

    #pragma unroll
    for (int k = 0; k < EPT; ++k) {
        const int e = (w * EPT + k) * GNY + lane;   // coalesced
        const float dv = entries[e];
        AT(isd2, k) = rsqrtf(dv);                   // D^-1/2 (exact for any pos diag)
        AT(rv2, k)  = bvec[e] * AT(isd2, k);        // r0 = b' (x0 = 0)
        AT(xv2, k) = 0.f; AT(pv2, k) = 0.f; AT(sv2, k) = 0.f;
    }

    float alpha = 0.f, ialpha = 0.f, rgam = 0.f, stop = 0.f;

    for (int it = 0; it < MAXIT; ++it) {
        // ---- phase 1: u = M^-1 r = r + isd.*Adj(isd.*r) ----
        #pragma unroll
        for (int m = 0; m < EPH; ++m) tv2[m] = isd2[m] * rv2[m];   // v_pk_mul
        halo1[w][0][lane] = AT(tv2, 0);
        halo1[w][1][lane] = AT(tv2, EPT - 1);
        #pragma unroll
        for (int k = 1; k < EPT - 1; ++k) {
            const float s4 = dpp0<DPP_WAVE_ROR1>(AT(tv2, k)) + dpp0<DPP_WAVE_ROL1>(AT(tv2, k))
                           + AT(tv2, k - 1) + AT(tv2, k + 1);
            AT(uv2, k) = fmaf(AT(isd2, k), s4, AT(rv2, k));
        }
        const float a30 = dpp0<DPP_WAVE_ROR1>(AT(tv2, 0)) + dpp0<DPP_WAVE_ROL1>(AT(tv2, 0))
                        + AT(tv2, 1);
        const float a3f = dpp0<DPP_WAVE_ROR1>(AT(tv2, EPT-1)) + dpp0<DPP_WAVE_ROL1>(AT(tv2, EPT-1))
                        + AT(tv2, EPT - 2);
        __syncthreads();                                        // BAR1
        {
            const float up = halo1[(w + NW - 1) & (NW - 1)][1][lane];
            const float dn = halo1[(w + 1) & (NW - 1)][0][lane];
            AT(uv2, 0)       = fmaf(AT(isd2, 0),       a30 + up, AT(rv2, 0));
            AT(uv2, EPT - 1) = fmaf(AT(isd2, EPT - 1), a3f + dn, AT(rv2, EPT - 1));
        }
        // gamma = r.u, packed accumulate (v_pk_fma)
        f32x2 gp2 = {0.f, 0.f};
        #pragma unroll
        for (int m = 0; m < EPH; ++m) gp2 = rv2[m] * uv2[m] + gp2;

        // ---- phase 2: w = S u = u - isd.*Adj(isd.*u) ----
        #pragma unroll
        for (int m = 0; m < EPH; ++m) tv2[m] = isd2[m] * uv2[m];   // v_pk_mul
        halo2[w][0][lane] = AT(tv2, 0);
        halo2[w][1][lane] = AT(tv2, EPT - 1);
        #pragma unroll
        for (int k = 1; k < EPT - 1; ++k) {
            const float s4 = dpp0<DPP_WAVE_ROR1>(AT(tv2, k)) + dpp0<DPP_WAVE_ROL1>(AT(tv2, k))
                           + AT(tv2, k - 1) + AT(tv2, k + 1);
            AT(wv2, k) = fmaf(-AT(isd2, k), s4, AT(uv2, k));
        }
        const float b30 = dpp0<DPP_WAVE_ROR1>(AT(tv2, 0)) + dpp0<DPP_WAVE_ROL1>(AT(tv2, 0))
                        + AT(tv2, 1);
        const float b3f = dpp0<DPP_WAVE_ROR1>(AT(tv2, EPT-1)) + dpp0<DPP_WAVE_ROL1>(AT(tv2, EPT-1))
                        + AT(tv2, EPT - 2);
        __syncthreads();                                        // BAR2
        {
            const float up = halo2[(w + NW - 1) & (NW - 1)][1][lane];
            const float dn = halo2[(w + 1) & (NW - 1)][0][lane];
            AT(wv2, 0)       = fmaf(-AT(isd2, 0),       b30 + up, AT(uv2, 0));
            AT(wv2, EPT - 1) = fmaf(-AT(isd2, EPT - 1), b3f + dn, AT(uv2, EPT - 1));
        }
        // delta = u.w, packed accumulate
        f32x2 dp2 = {0.f, 0.f};
        #pragma unroll
        for (int m = 0; m < EPH; ++m) dp2 = uv2[m] * wv2[m] + dp2;

        // ---- one fused reduction {gamma, delta} ----
        float gp = gp2[0] + gp2[1];
        float dp = dp2[0] + dp2[1];
        wave_sum2(gp, dp);                          // totals in lane 63
        if (lane == 63) red[w] = make_float2(gp, dp);
        __syncthreads();                                        // BAR3
        float ga, da;
        {
            const float2 pr = red[lane & (NW - 1)]; // broadcast ds_read_b64
            ga = pr.x; da = pr.y;
            row_sum16_2(ga, da);                    // totals in lane 15 of each row
            ga = rdlane(ga, 15);
            da = rdlane(da, 15);
        }

        float beta;
        if (it == 0) {
            beta = 0.f;
            const float rg = frcp(ga);
            alpha  = ga * frcp(da);
            ialpha = da * rg;                       // 1/alpha
            rgam   = rg;                            // 1/gamma
            stop   = ga * 3e-8f;
        } else {
            if (ga <= stop) break;                  // block-uniform -> deterministic
            const float rg = frcp(ga);
            beta = ga * rgam;
            const float denom = da - beta * ga * ialpha;
            alpha  = ga * frcp(denom);
            ialpha = denom * rg;
            rgam   = rg;
        }

        // ---- recurrences, packed (v_pk_fma); s = S p exactly: s = w + beta*s
        const f32x2 be  = {beta, beta};
        const f32x2 al  = {alpha, alpha};
        const f32x2 nal = {-alpha, -alpha};
        #pragma unroll
        for (int m = 0; m < EPH; ++m) {
            pv2[m] = be  * pv2[m] + uv2[m];
            sv2[m] = be  * sv2[m] + wv2[m];
            xv2[m] = al  * pv2[m] + xv2[m];
            rv2[m] = nal * sv2[m] + rv2[m];
        }
    }

    // unscale: x = isd .* x'
    #pragma unroll
    for (int k = 0; k < EPT; ++k)
        xout[(w * EPT + k) * GNY + lane] = AT(isd2, k) * AT(xv2, k);
}

extern "C" void kernel_launch(void* const* d_in, const int* in_sizes, int n_in,
                              void* d_out, int out_size, void* d_ws, size_t ws_size,
                              hipStream_t stream) {
    const float* entries = (const float*)d_in[0];   // entries_a [5N] f32 (diag first N)
    // d_in[1] = indices_a (static stencil), d_in[2] = eps_diag (unused by reference)
    const float* b = (const float*)d_in[3];         // b [N] f32
    float* xout = (float*)d_out;                    // x [N] f32

    pcg_neumann_kernel<<<1, TPB, 0, stream>>>(entries, b, xout);
}